// Round 5
// baseline (740.622 us; speedup 1.0000x reference)
//
#include <hip/hip_runtime.h>
#include <hip/hip_bf16.h>
#include <math.h>

#define N_NODES 131072
#define N_EDGES 1048576
#define B_GR    128
#define NPG_    1024
#define KTOP    30

// ---------------- CSR build ----------------

__global__ __launch_bounds__(256) void k_count(const int* __restrict__ dst, int* __restrict__ cnt) {
    int e = blockIdx.x * 256 + threadIdx.x;
    if (e < N_EDGES) atomicAdd(&cnt[dst[e]], 1);
}

__global__ __launch_bounds__(256) void k_scan1(const int* __restrict__ cnt,
                                               int* __restrict__ row_start,
                                               int* __restrict__ blocksum) {
    __shared__ int s[256];
    int t = threadIdx.x;
    int i = blockIdx.x * 256 + t;
    int v = cnt[i];
    s[t] = v; __syncthreads();
    for (int o = 1; o < 256; o <<= 1) {
        int x = (t >= o) ? s[t - o] : 0;
        __syncthreads();
        s[t] += x;
        __syncthreads();
    }
    row_start[i] = s[t] - v;
    if (t == 255) blocksum[blockIdx.x] = s[t];
}

__global__ __launch_bounds__(512) void k_scan2(int* __restrict__ blocksum) {
    __shared__ int s[512];
    int t = threadIdx.x;
    int v = blocksum[t];
    s[t] = v; __syncthreads();
    for (int o = 1; o < 512; o <<= 1) {
        int x = (t >= o) ? s[t - o] : 0;
        __syncthreads();
        s[t] += x;
        __syncthreads();
    }
    blocksum[t] = s[t] - v;
}

__global__ __launch_bounds__(256) void k_scan3(int* __restrict__ row_start,
                                               const int* __restrict__ blocksum,
                                               int* __restrict__ cursor) {
    int i = blockIdx.x * 256 + threadIdx.x;
    int r = row_start[i] + blocksum[blockIdx.x];
    row_start[i] = r;
    cursor[i] = r;
}

__global__ __launch_bounds__(256) void k_fill(const int* __restrict__ src,
                                              const int* __restrict__ dst,
                                              int* __restrict__ cursor,
                                              int2* __restrict__ csr) {
    int e = blockIdx.x * 256 + threadIdx.x;
    if (e < N_EDGES) {
        int d = dst[e];
        int pos = atomicAdd(&cursor[d], 1);
        csr[pos] = make_int2(src[e], e);
    }
}

// ---------------- fused: esum gather + z0 = [nf | esum] @ W0  (64 nodes/block)

__global__ __launch_bounds__(256) void k_z0fused(const float* __restrict__ nf,
                                                 const float* __restrict__ ef,
                                                 const int* __restrict__ row_start,
                                                 const int* __restrict__ cnt,
                                                 const int2* __restrict__ csr,
                                                 const float* __restrict__ W0,
                                                 float* __restrict__ z0) {
    __shared__ float a[64 * 161];     // row n: [0..127]=nf, [128..159]=esum; stride 161 -> (lane+k)%32 banks
    int tid = threadIdx.x;
    int n0 = blockIdx.x * 64;
    // stage nf tile (64 x 128) coalesced
    const float* nfb = nf + (size_t)n0 * 128;
    for (int f = tid; f < 8192; f += 256) {
        int nl = f >> 7, k = f & 127;
        a[nl * 161 + k] = nfb[f];
    }
    // gather esum per node: 8 groups x 8 nodes
    int g = tid >> 5, j = tid & 31;
    for (int q = 0; q < 8; ++q) {
        int nl = g * 8 + q;
        int n = n0 + nl;
        int start = row_start[n], len = cnt[n];
        const int2* ce = csr + start;
        float s = 0.f;
        int i = 0;
        for (; i + 8 <= len; i += 8) {
            int e0 = ce[i].y, e1 = ce[i + 1].y, e2 = ce[i + 2].y, e3 = ce[i + 3].y;
            int e4 = ce[i + 4].y, e5 = ce[i + 5].y, e6 = ce[i + 6].y, e7 = ce[i + 7].y;
            float a0 = ef[(size_t)e0 * 32 + j], a1 = ef[(size_t)e1 * 32 + j];
            float a2 = ef[(size_t)e2 * 32 + j], a3 = ef[(size_t)e3 * 32 + j];
            float a4 = ef[(size_t)e4 * 32 + j], a5 = ef[(size_t)e5 * 32 + j];
            float a6 = ef[(size_t)e6 * 32 + j], a7 = ef[(size_t)e7 * 32 + j];
            s += ((a0 + a1) + (a2 + a3)) + ((a4 + a5) + (a6 + a7));
        }
        for (; i < len; ++i) s += ef[(size_t)ce[i].y * 32 + j];
        a[nl * 161 + 128 + j] = s;
    }
    __syncthreads();
    // SGPR-weight GEMM: lane = node, wave = 8-col group
    int wv = __builtin_amdgcn_readfirstlane(tid >> 6);
    int lane = tid & 63;
    int c0 = wv * 8;
    float acc[8] = {0.f, 0.f, 0.f, 0.f, 0.f, 0.f, 0.f, 0.f};
    const float* ar = a + lane * 161;
    for (int k = 0; k < 160; ++k) {
        float av = ar[k];
        #pragma unroll
        for (int jj = 0; jj < 8; ++jj)
            acc[jj] += av * W0[k * 32 + c0 + jj];
    }
    float* zr = z0 + (size_t)(n0 + lane) * 32 + c0;
    *(float4*)zr = make_float4(acc[0], acc[1], acc[2], acc[3]);
    *(float4*)(zr + 4) = make_float4(acc[4], acc[5], acc[6], acc[7]);
}

// ---------------- fused: h = tanh((z_self+sum z_nb+b)/deg); z_next = h @ Wnext

__global__ __launch_bounds__(256) void k_gfused(const float* __restrict__ zin,
                                                const int* __restrict__ row_start,
                                                const int* __restrict__ cnt,
                                                const int2* __restrict__ csr,
                                                const float* __restrict__ bias,
                                                const float* __restrict__ Wnext,
                                                float* __restrict__ hout,
                                                float* __restrict__ zout) {
    __shared__ float a[64 * 33];
    int tid = threadIdx.x;
    int n0 = blockIdx.x * 64;
    int g = tid >> 5, j = tid & 31;
    float bj = bias[j];
    for (int q = 0; q < 8; ++q) {
        int nl = g * 8 + q;
        int n = n0 + nl;
        int start = row_start[n], len = cnt[n];
        const int2* cs = csr + start;
        float p = zin[(size_t)n * 32 + j];
        int i = 0;
        for (; i + 8 <= len; i += 8) {
            int s0 = cs[i].x, s1 = cs[i + 1].x, s2 = cs[i + 2].x, s3 = cs[i + 3].x;
            int s4 = cs[i + 4].x, s5 = cs[i + 5].x, s6 = cs[i + 6].x, s7 = cs[i + 7].x;
            float a0 = zin[(size_t)s0 * 32 + j], a1 = zin[(size_t)s1 * 32 + j];
            float a2 = zin[(size_t)s2 * 32 + j], a3 = zin[(size_t)s3 * 32 + j];
            float a4 = zin[(size_t)s4 * 32 + j], a5 = zin[(size_t)s5 * 32 + j];
            float a6 = zin[(size_t)s6 * 32 + j], a7 = zin[(size_t)s7 * 32 + j];
            p += ((a0 + a1) + (a2 + a3)) + ((a4 + a5) + (a6 + a7));
        }
        for (; i < len; ++i) p += zin[(size_t)cs[i].x * 32 + j];
        float deg = 1.f + (float)len;
        float h = tanhf((p + bj) / deg);
        hout[(size_t)n * 32 + j] = h;
        a[nl * 33 + j] = h;
    }
    __syncthreads();
    int wv = __builtin_amdgcn_readfirstlane(tid >> 6);
    int lane = tid & 63;
    int c0 = wv * 8;
    float acc[8] = {0.f, 0.f, 0.f, 0.f, 0.f, 0.f, 0.f, 0.f};
    const float* ar = a + lane * 33;
    #pragma unroll
    for (int k = 0; k < 32; ++k) {
        float av = ar[k];
        #pragma unroll
        for (int jj = 0; jj < 8; ++jj)
            acc[jj] += av * Wnext[k * 32 + c0 + jj];
    }
    float* zr = zout + (size_t)(n0 + lane) * 32 + c0;
    *(float4*)zr = make_float4(acc[0], acc[1], acc[2], acc[3]);
    *(float4*)(zr + 4) = make_float4(acc[4], acc[5], acc[6], acc[7]);
}

// ---------------- last 32-wide layer: h2 + premultiplied scalar z3 = h2 @ W3

__global__ __launch_bounds__(256) void k_g2(const float* __restrict__ zin,
                                            const int* __restrict__ row_start,
                                            const int* __restrict__ cnt,
                                            const int2* __restrict__ csr,
                                            const float* __restrict__ bias,
                                            const float* __restrict__ W3,
                                            float* __restrict__ hout,
                                            float* __restrict__ z3) {
    int g = threadIdx.x >> 5, j = threadIdx.x & 31;
    int n = blockIdx.x * 8 + g;
    int start = row_start[n], len = cnt[n];
    const int2* cs = csr + start;
    float p = zin[(size_t)n * 32 + j];
    int i = 0;
    for (; i + 8 <= len; i += 8) {
        int s0 = cs[i].x, s1 = cs[i + 1].x, s2 = cs[i + 2].x, s3 = cs[i + 3].x;
        int s4 = cs[i + 4].x, s5 = cs[i + 5].x, s6 = cs[i + 6].x, s7 = cs[i + 7].x;
        float a0 = zin[(size_t)s0 * 32 + j], a1 = zin[(size_t)s1 * 32 + j];
        float a2 = zin[(size_t)s2 * 32 + j], a3 = zin[(size_t)s3 * 32 + j];
        float a4 = zin[(size_t)s4 * 32 + j], a5 = zin[(size_t)s5 * 32 + j];
        float a6 = zin[(size_t)s6 * 32 + j], a7 = zin[(size_t)s7 * 32 + j];
        p += ((a0 + a1) + (a2 + a3)) + ((a4 + a5) + (a6 + a7));
    }
    for (; i < len; ++i) p += zin[(size_t)cs[i].x * 32 + j];
    float deg = 1.f + (float)len;
    float h = tanhf((p + bias[j]) / deg);
    hout[(size_t)n * 32 + j] = h;
    float t = h * W3[j];
    #pragma unroll
    for (int o = 16; o; o >>= 1) t += __shfl_xor(t, o, 32);
    if (j == 0) z3[n] = t;
}

// ---------------- layer 3: scalar gather-sum -> val

__global__ __launch_bounds__(256) void k_g3(const float* __restrict__ z3,
                                            const int* __restrict__ row_start,
                                            const int* __restrict__ cnt,
                                            const int2* __restrict__ csr,
                                            const float* __restrict__ b3,
                                            float* __restrict__ val) {
    int n = blockIdx.x * 256 + threadIdx.x;
    int start = row_start[n], len = cnt[n];
    const int2* cs = csr + start;
    float s = z3[n];
    int i = 0;
    for (; i + 4 <= len; i += 4)
        s += z3[cs[i].x] + z3[cs[i + 1].x] + z3[cs[i + 2].x] + z3[cs[i + 3].x];
    for (; i < len; ++i) s += z3[cs[i].x];
    float deg = 1.f + (float)len;
    val[n] = tanhf((s + b3[0]) / deg);
}

// ---------------- top-k + conv head, one block per graph ----------------

__global__ __launch_bounds__(256) void k_head(const float* __restrict__ h0,
                                              const float* __restrict__ h1,
                                              const float* __restrict__ h2,
                                              const float* __restrict__ val,
                                              const float* __restrict__ wc1,
                                              const float* __restrict__ bc1,
                                              const float* __restrict__ wc2,
                                              const float* __restrict__ bc2,
                                              const float* __restrict__ wout,
                                              const float* __restrict__ bout,
                                              float* __restrict__ out) {
    __shared__ float vals[1024];
    __shared__ int selidx[KTOP];
    __shared__ float sp[KTOP * 97];
    __shared__ float y1[16 * 30];
    __shared__ float pool[16 * 15];
    __shared__ float y2[352];
    int b = blockIdx.x, tid = threadIdx.x;
    const float* vb = val + (size_t)b * NPG_;
    for (int u = tid; u < NPG_; u += 256) vals[u] = vb[u];
    __syncthreads();
    if (tid < 64) {
        unsigned long long keys[16];
        #pragma unroll
        for (int r = 0; r < 16; ++r) {
            int u = tid * 16 + r;
            unsigned int bb = __float_as_uint(vals[u]);
            unsigned int ord = (bb & 0x80000000u) ? ~bb : (bb | 0x80000000u);
            keys[r] = ((unsigned long long)ord << 32) |
                      (unsigned long long)(0xFFFFFFFFu - (unsigned int)u);
        }
        for (int k = 0; k < KTOP; ++k) {
            unsigned long long m = keys[0];
            #pragma unroll
            for (int r = 1; r < 16; ++r) m = (keys[r] > m) ? keys[r] : m;
            #pragma unroll
            for (int o = 32; o; o >>= 1) {
                unsigned long long t = __shfl_xor(m, o);
                m = (t > m) ? t : m;
            }
            int u = (int)(0xFFFFFFFFu - (unsigned int)(m & 0xFFFFFFFFull));
            if (tid == 0) selidx[k] = u;
            #pragma unroll
            for (int r = 0; r < 16; ++r)
                if (tid * 16 + r == u) keys[r] = 0ull;
        }
    }
    __syncthreads();
    size_t nb = (size_t)b * NPG_;
    for (int idx = tid; idx < KTOP * 32; idx += 256) {
        int t = idx >> 5, d = idx & 31;
        size_t s = (nb + (size_t)selidx[t]) * 32;
        sp[t * 97 + d]      = h0[s + d];
        sp[t * 97 + 32 + d] = h1[s + d];
        sp[t * 97 + 64 + d] = h2[s + d];
    }
    if (tid < KTOP) sp[tid * 97 + 96] = vb[selidx[tid]];
    __syncthreads();
    for (int idx = tid; idx < 480; idx += 256) {
        int t = idx >> 4, c = idx & 15;
        float acc = bc1[c];
        for (int d = 0; d < 97; ++d) acc += sp[t * 97 + d] * wc1[c * 97 + d];
        y1[c * 30 + t] = fmaxf(acc, 0.f);
    }
    __syncthreads();
    for (int idx = tid; idx < 240; idx += 256) {
        int c = idx / 15, u = idx - c * 15;
        pool[c * 15 + u] = fmaxf(y1[c * 30 + 2 * u], y1[c * 30 + 2 * u + 1]);
    }
    __syncthreads();
    for (int idx = tid; idx < 352; idx += 256) {
        int o = idx / 11, t = idx - o * 11;
        float acc = bc2[o];
        for (int i = 0; i < 16; ++i)
            for (int kk = 0; kk < 5; ++kk)
                acc += pool[i * 15 + t + kk] * wc2[(o * 16 + i) * 5 + kk];
        y2[idx] = fmaxf(acc, 0.f);
    }
    __syncthreads();
    if (tid < 2) {
        float acc = bout[tid];
        for (int m = 0; m < 352; ++m) acc += y2[m] * wout[m * 2 + tid];
        out[b * 2 + tid] = fmaxf(acc, 0.f);
    }
}

// ---------------- launch ----------------

extern "C" void kernel_launch(void* const* d_in, const int* in_sizes, int n_in,
                              void* d_out, int out_size, void* d_ws, size_t ws_size,
                              hipStream_t stream) {
    const float* node_feat = (const float*)d_in[0];
    const float* edge_feat = (const float*)d_in[1];
    const int*   eidx      = (const int*)d_in[2];
    const float* W0 = (const float*)d_in[3];
    const float* b0 = (const float*)d_in[4];
    const float* W1 = (const float*)d_in[5];
    const float* b1 = (const float*)d_in[6];
    const float* W2 = (const float*)d_in[7];
    const float* b2 = (const float*)d_in[8];
    const float* W3 = (const float*)d_in[9];
    const float* b3 = (const float*)d_in[10];
    const float* wc1 = (const float*)d_in[11];
    const float* bc1 = (const float*)d_in[12];
    const float* wc2 = (const float*)d_in[13];
    const float* bc2 = (const float*)d_in[14];
    const float* wout = (const float*)d_in[15];
    const float* bout = (const float*)d_in[16];
    float* out = (float*)d_out;

    const int* src = eidx;
    const int* dst = eidx + N_EDGES;

    char* ws = (char*)d_ws;
    size_t off = 0;
    auto alloc = [&](size_t bytes) -> char* {
        char* p = ws + off;
        off += (bytes + 255) & ~(size_t)255;
        return p;
    };
    int* cnt       = (int*)alloc((size_t)N_NODES * 4);
    int* row_start = (int*)alloc((size_t)N_NODES * 4);
    int* cursor    = (int*)alloc((size_t)N_NODES * 4);
    int* blocksum  = (int*)alloc(512 * 4);
    int2* csr      = (int2*)alloc((size_t)N_EDGES * 8);
    float* z0      = (float*)alloc((size_t)N_NODES * 32 * 4);
    float* z1      = (float*)alloc((size_t)N_NODES * 32 * 4);
    float* z2      = (float*)alloc((size_t)N_NODES * 32 * 4);
    float* h0      = (float*)alloc((size_t)N_NODES * 32 * 4);
    float* h1      = (float*)alloc((size_t)N_NODES * 32 * 4);
    float* h2      = (float*)alloc((size_t)N_NODES * 32 * 4);
    float* z3      = (float*)alloc((size_t)N_NODES * 4);
    float* val     = (float*)alloc((size_t)N_NODES * 4);
    (void)ws_size;

    hipMemsetAsync(cnt, 0, (size_t)N_NODES * 4, stream);
    k_count<<<N_EDGES / 256, 256, 0, stream>>>(dst, cnt);
    k_scan1<<<N_NODES / 256, 256, 0, stream>>>(cnt, row_start, blocksum);
    k_scan2<<<1, 512, 0, stream>>>(blocksum);
    k_scan3<<<N_NODES / 256, 256, 0, stream>>>(row_start, blocksum, cursor);
    k_fill<<<N_EDGES / 256, 256, 0, stream>>>(src, dst, cursor, csr);
    k_z0fused<<<N_NODES / 64, 256, 0, stream>>>(node_feat, edge_feat, row_start, cnt, csr, W0, z0);
    k_gfused<<<N_NODES / 64, 256, 0, stream>>>(z0, row_start, cnt, csr, b0, W1, h0, z1);
    k_gfused<<<N_NODES / 64, 256, 0, stream>>>(z1, row_start, cnt, csr, b1, W2, h1, z2);
    k_g2<<<N_NODES / 8, 256, 0, stream>>>(z2, row_start, cnt, csr, b2, W3, h2, z3);
    k_g3<<<N_NODES / 256, 256, 0, stream>>>(z3, row_start, cnt, csr, b3, val);
    k_head<<<B_GR, 256, 0, stream>>>(h0, h1, h2, val, wc1, bc1, wc2, bc2, wout, bout, out);
}